// Round 17
// baseline (421.052 us; speedup 1.0000x reference)
//
#include <hip/hip_runtime.h>
#include <hip/hip_bf16.h>
#include <math.h>

typedef __hip_bfloat16 bf16;
typedef __attribute__((ext_vector_type(8))) short bf16x8;
typedef __attribute__((ext_vector_type(4))) float f32x4;

#define NB 32
#define NC 32
#define NNODE 300
#define NT 64
#define NDIM 40
#define KTOP 20
#define NSKIP 64
#define NTOUT 58
#define SLAB 17400        // NNODE*NTOUT (out layout)
#define BSLAB 556800      // NC*SLAB
#define XEL 17817600      // NB*BSLAB
#define PSLAB 2048        // 64 t x 32 c node slab (channel-minor)
#define BPSLAB 614400     // NNODE*PSLAB
#define XPEL 19660800     // NB*BPSLAB

__device__ __forceinline__ float b2f(bf16 v){ return __bfloat162float(v); }
__device__ __forceinline__ bf16 f2b(float v){ return __float2bfloat16(v); }
__device__ __forceinline__ float fsig(float x){ return 1.0f/(1.0f + __expf(-x)); }
__device__ __forceinline__ float ftanh(float x){ return 2.0f*fsig(2.0f*x) - 1.0f; }

__device__ __forceinline__ unsigned short bbits(float v){
  bf16 h = f2b(v); unsigned short s; __builtin_memcpy(&s, &h, 2); return s;
}

__device__ __forceinline__ uint4 pack8(const float f[8]){
  uint4 d;
  d.x = (unsigned)bbits(f[0]) | ((unsigned)bbits(f[1]) << 16);
  d.y = (unsigned)bbits(f[2]) | ((unsigned)bbits(f[3]) << 16);
  d.z = (unsigned)bbits(f[4]) | ((unsigned)bbits(f[5]) << 16);
  d.w = (unsigned)bbits(f[6]) | ((unsigned)bbits(f[7]) << 16);
  return d;
}

// XCD-aware swizzle for 9600-block kernels
__device__ __forceinline__ void bv_swz(int bid, int& b, int& v){
  int xcd = bid & 7, i = bid >> 3;
  int nb = xcd*1200 + i;
  b = nb / NNODE; v = nb - b*NNODE;
}

// ---------------- graph construction ----------------
__global__ void k_nodes(const float* __restrict__ emb1, const float* __restrict__ emb2,
                        const float* __restrict__ l1w, const float* __restrict__ l1b,
                        const float* __restrict__ l2w, const float* __restrict__ l2b,
                        const int* __restrict__ idxp,
                        float* __restrict__ n1, float* __restrict__ n2){
  int i = blockIdx.x; int d = threadIdx.x;
  if (d >= NDIM) return;
  int r = idxp[i];
  float a1 = l1b[d], a2 = l2b[d];
  for (int k=0;k<NDIM;++k){
    a1 = fmaf(emb1[r*NDIM+k], l1w[d*NDIM+k], a1);
    a2 = fmaf(emb2[r*NDIM+k], l2w[d*NDIM+k], a2);
  }
  n1[i*NDIM+d] = tanhf(3.0f*a1);
  n2[i*NDIM+d] = tanhf(3.0f*a2);
}

__global__ void __launch_bounds__(64) k_adjrow(const float* __restrict__ n1,
                                               const float* __restrict__ n2,
                                               float* __restrict__ Am){
  int i = blockIdx.x; int lane = threadIdx.x;
  __shared__ float rowo[NNODE];
  __shared__ float rowv[NNODE];
  __shared__ int   sel[NNODE];
  for (int j=lane;j<NNODE;j+=64){
    float a = 0.f;
    #pragma unroll
    for (int k=0;k<NDIM;++k){
      float a1 = n1[i*NDIM+k], a2 = n2[i*NDIM+k];
      a = fmaf(a1, n2[j*NDIM+k], a);
      a = fmaf(-a2, n1[j*NDIM+k], a);
    }
    float v = tanhf(3.0f*a);
    v = v > 0.f ? v : 0.f;
    rowo[j]=v; rowv[j]=v; sel[j]=0;
  }
  __syncthreads();
  for (int it=0; it<KTOP; ++it){
    float best = -1.f; int bi = 0x7fffffff;
    for (int j=lane;j<NNODE;j+=64){
      float v = rowv[j];
      if (v > best){ best=v; bi=j; }
    }
    #pragma unroll
    for (int off=32; off; off>>=1){
      float ov = __shfl_xor(best, off);
      int   oi = __shfl_xor(bi, off);
      if (ov > best || (ov == best && oi < bi)){ best=ov; bi=oi; }
    }
    if (lane==0){ sel[bi]=1; rowv[bi]=-2.f; }
    __syncthreads();
  }
  for (int j=lane;j<NNODE;j+=64)
    Am[i*NNODE+j] = sel[j] ? rowo[j] : 0.f;
}

// ---------------- dense normalized adjacency Ah[2][304][304] fp32 (zero-padded) ----------------
__global__ void __launch_bounds__(64) k_norm(const float* __restrict__ Am, float* __restrict__ Ah){
  int r = blockIdx.x;                 // 0..607
  int side = r >= 304; int v = side ? r - 304 : r;
  float* dst = Ah + (size_t)(side ? 304*304 : 0) + v*304;
  int lane = threadIdx.x;
  if (v >= NNODE){
    for (int w=lane; w<304; w+=64) dst[w] = 0.f;
    return;
  }
  float s = 0.f;
  for (int w=lane; w<NNODE; w+=64)
    s += side ? Am[w*NNODE + v] : Am[v*NNODE + w];
  #pragma unroll
  for (int off=32; off; off>>=1) s += __shfl_xor(s, off);
  float inv = 1.0f/(s + 1.0f);        // +1 for the diagonal
  for (int w=lane; w<304; w+=64){
    float a = (w < NNODE) ? (side ? Am[w*NNODE + v] : Am[v*NNODE + w]) : 0.f;
    if (w == v) a += 1.0f;
    dst[w] = a*inv;
  }
}

// ---------------- M matrices -> MFMA A-fragment pack ----------------
// M1 = 0.05I + 0.95*Ah ; M2 = 0.05I + 0.0475*Ah + 0.9025*Ah^2, per side. pm = side*2 + m.
__global__ void k_mpk(const float* __restrict__ Ah, bf16* __restrict__ Mpk){
  int id = blockIdx.x*blockDim.x + threadIdx.x;
  if (id >= 4*320*320) return;
  int pm = id / (320*320);
  int rem = id % (320*320);
  int v = rem / 320, w = rem % 320;
  int s = pm >> 1, m = pm & 1;
  float val = 0.f;
  if (v < 304 && w < 304){
    const float* A = Ah + (size_t)s*304*304;
    float a = A[v*304 + w];
    if (m == 0){
      val = 0.95f*a + (v==w ? 0.05f : 0.f);
    } else {
      float d = 0.f;
      for (int u=0; u<304; ++u) d = fmaf(A[v*304 + u], A[u*304 + w], d);
      val = 0.9025f*d + 0.0475f*a + (v==w ? 0.05f : 0.f);
    }
  }
  int vt16 = v >> 4, lv = v & 15, ks = w >> 5, g = (w >> 3) & 3, j = w & 7;
  int lane = g*16 + lv;
  Mpk[(((size_t)(pm*20 + vt16)*10 + ks)*64 + lane)*8 + j] = f2b(val);
}

// ---------------- inception weights packed per-tap: wfA[((mt*7 + d)*64 + lane)*8 + j] ----------------
__global__ void k_wpack2(const float* __restrict__ fw2,const float* __restrict__ fw3,
                         const float* __restrict__ fw6,const float* __restrict__ fw7,
                         const float* __restrict__ gw2,const float* __restrict__ gw3,
                         const float* __restrict__ gw6,const float* __restrict__ gw7,
                         const float* __restrict__ fb2,const float* __restrict__ fb3,
                         const float* __restrict__ fb6,const float* __restrict__ fb7,
                         const float* __restrict__ gb2,const float* __restrict__ gb3,
                         const float* __restrict__ gb6,const float* __restrict__ gb7,
                         bf16* __restrict__ wfA, float* __restrict__ biasPk){
  int T = blockIdx.x*blockDim.x + threadIdx.x;
  if (T < 14336){
    int j = T & 7;
    int l = (T >> 3) & 63;
    int q = T >> 9;               // 0..27
    int d = q % 7, mt = q / 7;
    int m = mt*16 + (l & 15);
    int ic = (l >> 4)*8 + j;
    int c = m >> 1, path = m & 1;
    int cls = c >> 3, o = c & 7;
    int kk = (cls==0) ? 2 : (cls==1) ? 3 : (cls==2) ? 6 : 7;
    int tp = d - (7 - kk);
    float val = 0.f;
    if (tp >= 0){
      const float* w = (path==0)
        ? (cls==0?fw2:cls==1?fw3:cls==2?fw6:fw7)
        : (cls==0?gw2:cls==1?gw3:cls==2?gw6:gw7);
      val = w[(o*NC + ic)*kk + tp];
    }
    wfA[T] = f2b(val);
  } else if (T < 14336 + 32){
    int c = T - 14336;
    int cls = c >> 3, o = c & 7;
    const float* fb = cls==0?fb2:cls==1?fb3:cls==2?fb6:fb7;
    const float* gb = cls==0?gb2:cls==1?gb3:cls==2?gb6:gb7;
    biasPk[c*2]   = fb[o];
    biasPk[c*2+1] = gb[o];
  }
}

// ---------------- mix conv weights as B-fragments (two-buffer form) ----------------
__global__ void k_wprepM(const float* __restrict__ m1w, const float* __restrict__ m2w,
                         const float* __restrict__ m1b, const float* __restrict__ m2b,
                         bf16* __restrict__ pkB0, bf16* __restrict__ pkB1,
                         float* __restrict__ biasSum){
  int id = blockIdx.x*blockDim.x + threadIdx.x;
  if (id < 3072){
    int j = id & 7, l = (id >> 3) & 63, q = id >> 9;   // q = nt*3+ks
    int ks = q % 3, nt = q / 3;
    int k = (l >> 4)*8 + j;
    int c = nt*16 + (l & 15);
    float val;
    if      (ks == 0) val = m1w[c*96 + k] + m2w[c*96 + k];
    else if (ks == 1) val = m1w[c*96 + 32 + k];
    else              val = m1w[c*96 + 64 + k];
    pkB0[id] = f2b(val);
  } else if (id < 5120){
    int id2 = id - 3072;
    int j = id2 & 7, l = (id2 >> 3) & 63, q = id2 >> 9; // q = nt*2+ks
    int ks = q & 1, nt = q >> 1;
    int k = (l >> 4)*8 + j;
    int c = nt*16 + (l & 15);
    pkB1[id2] = f2b(ks==0 ? m2w[c*96 + 32 + k] : m2w[c*96 + 64 + k]);
  } else if (id < 5152){
    int c = id - 5120;
    biasSum[c] = m1b[c] + m2b[c];
  }
}

// ---------------- skip weights packed as MFMA B-fragments ----------------
__global__ void k_wTb(const float* __restrict__ sw, bf16* __restrict__ wTb){
  int id = blockIdx.x*blockDim.x + threadIdx.x;
  if (id >= 131072) return;
  int j = id & 7, l = (id >> 3) & 63, q = id >> 9;  // q = nt*64 + ks
  int ks = q & 63, nt = q >> 6;
  int k = ks*32 + (l >> 4)*8 + j;
  int t = k >> 5, c = k & 31;
  int sc = nt*16 + (l & 15);
  float val = (t < NTOUT) ? sw[sc*1856 + c*NTOUT + t] : 0.f;
  wTb[id] = f2b(val);
}

// ---------------- dilated inception via 7 shifted K=32 MFMAs -> Xp[b][n][t][c] ----------------
__global__ void __launch_bounds__(256) k_incepM(const float* __restrict__ x,
    const bf16* __restrict__ wfA, const float* __restrict__ biasPk,
    bf16* __restrict__ Xp){
  __shared__ unsigned short xcm[72*32];
  int b, n; bv_swz(blockIdx.x, b, n);
  int bn = b*NNODE + n;
  int tid = threadIdx.x;
  {
    int c = tid >> 3, tq = tid & 7, t0 = tq*8;
    const float* src = x + ((size_t)(b*NC + c)*NNODE + n)*NT + t0;
    float4 v0 = *reinterpret_cast<const float4*>(src);
    float4 v1 = *reinterpret_cast<const float4*>(src + 4);
    float f[8] = {v0.x,v0.y,v0.z,v0.w,v1.x,v1.y,v1.z,v1.w};
    int gl = c >> 3, cl = c & 7;
    #pragma unroll
    for (int i=0;i<8;++i){
      int t = t0 + i;
      int pg = gl ^ ((t >> 3) & 3);
      xcm[t*32 + pg*8 + cl] = bbits(f[i]);
    }
    int zt = 64 + (tid >> 5), zic = tid & 31;
    int zpg = (zic >> 3) ^ ((zt >> 3) & 3);
    xcm[zt*32 + zpg*8 + (zic & 7)] = 0;
  }
  __syncthreads();
  int lane = tid & 63;
  int mt = __builtin_amdgcn_readfirstlane(tid >> 6);
  bf16x8 wA[7];
  #pragma unroll
  for (int d=0; d<7; ++d)
    wA[d] = *reinterpret_cast<const bf16x8*>(wfA + (size_t)((mt*7 + d)*64 + lane)*8);
  int g = lane >> 4, col = lane & 15;
  int c0 = mt*8 + 2*g;
  float4 bias2 = *reinterpret_cast<const float4*>(biasPk + c0*2);
  #pragma unroll
  for (int nt=0; nt<4; ++nt){
    int t = col + nt*16;
    f32x4 acc = {0.f, 0.f, 0.f, 0.f};
    #pragma unroll
    for (int d=0; d<7; ++d){
      int tr = t + d;
      int pg = g ^ ((tr >> 3) & 3);
      bf16x8 bfr = *reinterpret_cast<const bf16x8*>(&xcm[tr*32 + pg*8]);
      acc = __builtin_amdgcn_mfma_f32_16x16x32_bf16(wA[d], bfr, acc, 0, 0, 0);
    }
    bool act = t < NTOUT;
    float X0 = act ? (ftanh(acc[0] + bias2.x) * fsig(acc[1] + bias2.y)) : 0.f;
    float X1 = act ? (ftanh(acc[2] + bias2.z) * fsig(acc[3] + bias2.w)) : 0.f;
    unsigned pv = (unsigned)bbits(X0) | ((unsigned)bbits(X1) << 16);
    *reinterpret_cast<unsigned*>(Xp + (size_t)bn*PSLAB + t*32 + c0) = pv;
  }
}

// ---------------- Xp transpose -> XpT2 k-tiled: [b][ctt 16][ks 10][ct_in 128][w_in 32] ----------------
__global__ void __launch_bounds__(256) k_xt(const bf16* __restrict__ Xp, bf16* __restrict__ XpT2){
  __shared__ unsigned short tile[64*66];
  int bid = blockIdx.x;
  int b = bid / 160, r = bid - b*160;
  int wt = r / 32, ctt2 = r - wt*32;
  int w0 = wt*64, ct0 = ctt2*64;
  int tid = threadIdx.x;
  #pragma unroll
  for (int p=0; p<2; ++p){
    int w_in = (tid >> 3) + p*32;
    int ct_in = (tid & 7)*8;
    int w = w0 + w_in;
    uint4 d = (w < NNODE)
      ? *reinterpret_cast<const uint4*>(Xp + (size_t)b*BPSLAB + (size_t)w*PSLAB + ct0 + ct_in)
      : make_uint4(0,0,0,0);
    unsigned short* t = tile + w_in*66 + ct_in;
    *reinterpret_cast<unsigned*>(t)     = d.x;
    *reinterpret_cast<unsigned*>(t + 2) = d.y;
    *reinterpret_cast<unsigned*>(t + 4) = d.z;
    *reinterpret_cast<unsigned*>(t + 6) = d.w;
  }
  __syncthreads();
  #pragma unroll
  for (int p=0; p<2; ++p){
    int ct_in = (tid >> 3) + p*32;
    int wq = tid & 7;
    unsigned short u[8];
    #pragma unroll
    for (int j=0;j<8;++j) u[j] = tile[(wq*8 + j)*66 + ct_in];
    uint4 d;
    d.x = (unsigned)u[0] | ((unsigned)u[1] << 16);
    d.y = (unsigned)u[2] | ((unsigned)u[3] << 16);
    d.z = (unsigned)u[4] | ((unsigned)u[5] << 16);
    d.w = (unsigned)u[6] | ((unsigned)u[7] << 16);
    int ct = ct0 + ct_in;
    int w = w0 + wq*8;
    int ks = w >> 5, w_in32 = w & 31;
    size_t addr = (((size_t)(b*16 + (ct >> 7))*10 + ks) << 12) + ((ct & 127) << 5) + w_in32;
    *reinterpret_cast<uint4*>(XpT2 + addr) = d;
  }
}

// ---------------- skip path via MFMA ----------------
__global__ void __launch_bounds__(256) k_skipM(const bf16* __restrict__ Xp, const bf16* __restrict__ wTb,
      const float* __restrict__ skip_b, const float* __restrict__ x_skip, float* __restrict__ out){
  int bn0 = blockIdx.x * 16;
  int tid = threadIdx.x, lane = tid & 63;
  int nt = __builtin_amdgcn_readfirstlane(tid >> 6);
  int g = lane >> 4, col = lane & 15;
  const bf16* aptr = Xp + (size_t)(bn0 + col)*PSLAB + g*8;
  const bf16* bptr = wTb + ((size_t)nt*64*64 + lane)*8;
  f32x4 acc = {0.f, 0.f, 0.f, 0.f};
  #pragma unroll 4
  for (int ks=0; ks<64; ++ks){
    bf16x8 aF = *reinterpret_cast<const bf16x8*>(aptr + ks*32);
    bf16x8 bF = *reinterpret_cast<const bf16x8*>(bptr + (size_t)ks*512);
    acc = __builtin_amdgcn_mfma_f32_16x16x32_bf16(aF, bF, acc, 0, 0, 0);
  }
  int sc = nt*16 + col;
  float sb = skip_b[sc];
  #pragma unroll
  for (int r=0;r<4;++r){
    int bn = bn0 + g*4 + r;
    int b = bn / NNODE, n = bn - b*NNODE;
    size_t so = (size_t)b*NSKIP*NNODE + (size_t)sc*NNODE + n;
    out[(size_t)XEL + so] = acc[r] + sb + x_skip[so];
  }
}

// ---------------- hop GEMM: H_m[b] = M_m,side x X ; B staged via LDS (pitch 72) ----------------
__global__ void __launch_bounds__(256) k_hop(const bf16* __restrict__ XpT2,
    const bf16* __restrict__ Mpk, bf16* __restrict__ H1, bf16* __restrict__ H2, int pass){
  __shared__ unsigned short bst[128*72];              // 18 KB, pitch 72 shorts
  __shared__ __align__(16) unsigned short outT[64*136];
  int bid = blockIdx.x;
  int xcd = bid & 7, i = bid >> 3;
  int nb = xcd*640 + i;
  int b = nb / 160; int r = nb - b*160;
  int m = r / 80; r -= m*80;
  int vt = r >> 4; int ctt = r & 15;
  int ct0 = ctt*128, v0 = vt*64;
  int tid = threadIdx.x, lane = tid & 63;
  int mt = __builtin_amdgcn_readfirstlane(tid >> 6);
  int g = lane >> 4, col = lane & 15;
  const bf16* mbase = Mpk + (((size_t)((pass*2 + m)*20 + vt*4 + mt)*10)*64 + lane)*8;
  bf16x8 aF[10];
  #pragma unroll
  for (int ks=0; ks<10; ++ks)
    aF[ks] = *reinterpret_cast<const bf16x8*>(mbase + (size_t)ks*512);
  const bf16* tb = XpT2 + (((size_t)(b*16 + ctt)*10) << 12);
  int s_ct = tid >> 2, s_w = (tid & 3)*8;
  f32x4 acc[8];
  #pragma unroll
  for (int nt=0; nt<8; ++nt) acc[nt] = (f32x4){0.f,0.f,0.f,0.f};
  for (int ks=0; ks<10; ++ks){
    __syncthreads();
    const bf16* src = tb + ((size_t)ks << 12);
    {
      uint4 d0 = *reinterpret_cast<const uint4*>(src + s_ct*32 + s_w);
      uint4 d1 = *reinterpret_cast<const uint4*>(src + (s_ct+64)*32 + s_w);
      *reinterpret_cast<uint4*>(bst + s_ct*72 + s_w)      = d0;
      *reinterpret_cast<uint4*>(bst + (s_ct+64)*72 + s_w) = d1;
    }
    __syncthreads();
    #pragma unroll
    for (int nt=0; nt<8; ++nt){
      bf16x8 bF = *reinterpret_cast<const bf16x8*>(bst + (nt*16 + col)*72 + g*8);
      acc[nt] = __builtin_amdgcn_mfma_f32_16x16x32_bf16(aF[ks], bF, acc[nt], 0, 0, 0);
    }
  }
  #pragma unroll
  for (int nt=0; nt<8; ++nt){
    #pragma unroll
    for (int r4=0; r4<4; ++r4)
      outT[(mt*16 + g*4 + r4)*136 + nt*16 + col] = bbits(acc[nt][r4]);
  }
  __syncthreads();
  bf16* Hout = (m == 0) ? H1 : H2;
  {
    int vl = tid >> 2, e = tid & 3;
    int v = v0 + vl;
    if (v < NNODE){
      bf16* dst = Hout + (size_t)b*BPSLAB + (size_t)v*PSLAB + ct0;
      #pragma unroll
      for (int h=0; h<4; ++h){
        int ctl = e*32 + h*8;
        uint4 d = *reinterpret_cast<const uint4*>(outT + vl*136 + ctl);
        *reinterpret_cast<uint4*>(dst + ctl) = d;
      }
    }
  }
}

// ---------------- fuse side 0: Xp <- bf16(bias + W0*X + W1a*H1 + W2a*H2)  (in-place partial) ----------------
__global__ void __launch_bounds__(256) k_fuse0(bf16* __restrict__ Xp,
    const bf16* __restrict__ H1, const bf16* __restrict__ H2,
    const bf16* __restrict__ pkB, const float* __restrict__ biasSum){
  int b, v; bv_swz(blockIdx.x, b, v);
  size_t vbase = (size_t)b*BPSLAB + (size_t)v*PSLAB;
  int tid = threadIdx.x, lane = tid & 63;
  int mt = __builtin_amdgcn_readfirstlane(tid >> 6);
  int g = lane >> 4, col = lane & 15;
  int tRow = mt*16 + col;
  bf16x8 aX = *reinterpret_cast<const bf16x8*>(Xp + vbase + tRow*32 + g*8);
  bf16x8 a1 = *reinterpret_cast<const bf16x8*>(H1 + vbase + tRow*32 + g*8);
  bf16x8 a2 = *reinterpret_cast<const bf16x8*>(H2 + vbase + tRow*32 + g*8);
  __syncthreads();            // all slab reads complete before in-place overwrite
  int t0 = mt*16 + g*4;
  bf16* pp = Xp + vbase;
  #pragma unroll
  for (int nt=0; nt<2; ++nt){
    int c_out = nt*16 + col;
    float bv = biasSum[c_out];
    f32x4 acc = {bv, bv, bv, bv};
    bf16x8 w0 = *reinterpret_cast<const bf16x8*>(pkB + (size_t)((nt*3+0)*64 + lane)*8);
    bf16x8 w1 = *reinterpret_cast<const bf16x8*>(pkB + (size_t)((nt*3+1)*64 + lane)*8);
    bf16x8 w2 = *reinterpret_cast<const bf16x8*>(pkB + (size_t)((nt*3+2)*64 + lane)*8);
    acc = __builtin_amdgcn_mfma_f32_16x16x32_bf16(aX, w0, acc, 0, 0, 0);
    acc = __builtin_amdgcn_mfma_f32_16x16x32_bf16(a1, w1, acc, 0, 0, 0);
    acc = __builtin_amdgcn_mfma_f32_16x16x32_bf16(a2, w2, acc, 0, 0, 0);
    #pragma unroll
    for (int r=0;r<4;++r)
      pp[(t0 + r)*32 + c_out] = f2b(acc[r]);
  }
}

// ---------------- fuse side 1: out = P + W1b*H1 + W2b*H2 + residual ; LN partial sums ----------------
// LDS-transposed epilogue: tile[c][t] (pitch 61), then coalesced t-contiguous read/write
__global__ void __launch_bounds__(256) k_fuse1(const bf16* __restrict__ P,
    const bf16* __restrict__ H1, const bf16* __restrict__ H2,
    float* __restrict__ out, const float* __restrict__ x,
    const bf16* __restrict__ pkB, double* __restrict__ part2){
  __shared__ float tile[32*61];
  __shared__ float redS[4], redS2[4];
  int b, v; bv_swz(blockIdx.x, b, v);
  size_t vbase = (size_t)b*BPSLAB + (size_t)v*PSLAB;
  int tid = threadIdx.x, lane = tid & 63;
  int mt = __builtin_amdgcn_readfirstlane(tid >> 6);
  int g = lane >> 4, col = lane & 15;
  int tRow = mt*16 + col;
  bf16x8 a1 = *reinterpret_cast<const bf16x8*>(H1 + vbase + tRow*32 + g*8);
  bf16x8 a2 = *reinterpret_cast<const bf16x8*>(H2 + vbase + tRow*32 + g*8);
  int t0 = mt*16 + g*4;
  const bf16* pp = P + vbase;
  #pragma unroll
  for (int nt=0; nt<2; ++nt){
    int c_out = nt*16 + col;
    f32x4 acc = {0.f, 0.f, 0.f, 0.f};
    bf16x8 w0 = *reinterpret_cast<const bf16x8*>(pkB + (size_t)((nt*2+0)*64 + lane)*8);
    bf16x8 w1 = *reinterpret_cast<const bf16x8*>(pkB + (size_t)((nt*2+1)*64 + lane)*8);
    acc = __builtin_amdgcn_mfma_f32_16x16x32_bf16(a1, w0, acc, 0, 0, 0);
    acc = __builtin_amdgcn_mfma_f32_16x16x32_bf16(a2, w1, acc, 0, 0, 0);
    #pragma unroll
    for (int r=0;r<4;++r){
      int t = t0 + r;
      if (t < NTOUT)
        tile[c_out*61 + t] = b2f(pp[t*32 + c_out]) + acc[r];
    }
  }
  __syncthreads();
  // coalesced epilogue: i = c*58 + t, consecutive tid -> consecutive t
  float s = 0.f, s2 = 0.f;
  size_t obase = ((size_t)(b*NC)*NNODE + v)*NTOUT;
  size_t xbase = ((size_t)(b*NC)*NNODE + v)*NT + 6;
  for (int i = tid; i < NC*NTOUT; i += 256){
    int c = i / NTOUT, t = i - c*NTOUT;
    float f = tile[c*61 + t] + x[xbase + (size_t)c*NNODE*NT + t];
    out[obase + (size_t)c*SLAB + t] = f;
    s  += f;
    s2 += f*f;
  }
  #pragma unroll
  for (int o=32; o; o>>=1){ s += __shfl_down(s, o); s2 += __shfl_down(s2, o); }
  int w = tid >> 6;
  if (lane == 0){ redS[w] = s; redS2[w] = s2; }
  __syncthreads();
  if (tid == 0){
    float as = redS[0]+redS[1]+redS[2]+redS[3];
    float as2 = redS2[0]+redS2[1]+redS2[2]+redS2[3];
    atomicAdd(&part2[b*2],   (double)as);
    atomicAdd(&part2[b*2+1], (double)as2);
  }
}

// ---------------- layernorm ----------------
__global__ void k_lnfin(const double* __restrict__ part2, float* __restrict__ stats){
  int b = threadIdx.x; if (b >= 32) return;
  double s = part2[b*2], s2 = part2[b*2+1];
  double n = (double)BSLAB;
  double mean = s/n;
  double var = s2/n - mean*mean;
  stats[b*2]   = (float)mean;
  stats[b*2+1] = (float)(1.0/sqrt(var + 1e-5));
}

__global__ void __launch_bounds__(256) k_lnapply(float* __restrict__ out, const float* __restrict__ stats,
        const float* __restrict__ lnw, const float* __restrict__ lnb, const int* __restrict__ idxp){
  int o = blockIdx.x*256 + threadIdx.x;
  int t = o % NTOUT; int v = (o / NTOUT) % NNODE; int c = (o / SLAB) % NC; int b = o / BSLAB;
  float mean = stats[b*2], rstd = stats[b*2+1];
  int vn = idxp[v];
  float wv = lnw[((size_t)c*NNODE + vn)*NTOUT + t];
  float bv = lnb[((size_t)c*NNODE + vn)*NTOUT + t];
  float vx = out[o];
  out[o] = (vx - mean)*rstd*wv + bv;
}

extern "C" void kernel_launch(void* const* d_in, const int* in_sizes, int n_in,
                              void* d_out, int out_size, void* d_ws, size_t ws_size,
                              hipStream_t stream) {
  (void)in_sizes; (void)n_in; (void)out_size; (void)ws_size;
  const float* x     = (const float*)d_in[0];
  const float* xskip = (const float*)d_in[1];
  const int*   idxp  = (const int*)d_in[2];
  const float* emb1  = (const float*)d_in[3];
  const float* emb2  = (const float*)d_in[4];
  const float* l1w   = (const float*)d_in[5];
  const float* l1b   = (const float*)d_in[6];
  const float* l2w   = (const float*)d_in[7];
  const float* l2b   = (const float*)d_in[8];
  const float* skw   = (const float*)d_in[9];
  const float* skb   = (const float*)d_in[10];
  const float* m1w   = (const float*)d_in[11];
  const float* m1b   = (const float*)d_in[12];
  const float* m2w   = (const float*)d_in[13];
  const float* m2b   = (const float*)d_in[14];
  const float* lnw   = (const float*)d_in[15];
  const float* lnb   = (const float*)d_in[16];
  const float* fw2=(const float*)d_in[17]; const float* fb2=(const float*)d_in[18];
  const float* gw2=(const float*)d_in[19]; const float* gb2=(const float*)d_in[20];
  const float* fw3=(const float*)d_in[21]; const float* fb3=(const float*)d_in[22];
  const float* gw3=(const float*)d_in[23]; const float* gb3=(const float*)d_in[24];
  const float* fw6=(const float*)d_in[25]; const float* fb6=(const float*)d_in[26];
  const float* gw6=(const float*)d_in[27]; const float* gb6=(const float*)d_in[28];
  const float* fw7=(const float*)d_in[29]; const float* fb7=(const float*)d_in[30];
  const float* gw7=(const float*)d_in[31]; const float* gb7=(const float*)d_in[32];
  float* out = (float*)d_out;

  char* wsbase = (char*)d_ws;
  size_t cur = 0;
  auto alloc = [&](size_t bytes)->char*{
    char* p = wsbase + cur;
    cur = (cur + bytes + 255) & ~(size_t)255;
    return p;
  };
  bf16*  Xp   = (bf16*) alloc((size_t)XPEL*2);
  bf16*  H1   = (bf16*) alloc((size_t)XPEL*2);
  bf16*  H2   = (bf16*) alloc((size_t)XPEL*2);
  bf16*  XpT2 = (bf16*) alloc((size_t)NB*16*10*4096*2);
  float* n1   = (float*)alloc(12000*4);
  float* n2   = (float*)alloc(12000*4);
  float* Am   = (float*)alloc(90000*4);
  float* Ah   = (float*)alloc(2*304*304*4);
  bf16*  Mpk  = (bf16*) alloc((size_t)4*20*10*64*8*2);
  bf16*  wTb  = (bf16*) alloc(131072*2);
  bf16*  wfA  = (bf16*) alloc(14336*2);
  float* biasPk = (float*)alloc(64*4);
  bf16*  pkB0 = (bf16*) alloc(3072*2);
  bf16*  pkB1 = (bf16*) alloc(2048*2);
  float* biasSum = (float*)alloc(32*4);
  double* part2 = (double*)alloc(64*8);
  float* stats = (float*)alloc(64*4);

  hipMemsetAsync(part2, 0, 64*sizeof(double), stream);

  // graph construction
  k_nodes <<<NNODE, 64, 0, stream>>>(emb1, emb2, l1w, l1b, l2w, l2b, idxp, n1, n2);
  k_adjrow<<<NNODE, 64, 0, stream>>>(n1, n2, Am);
  k_norm  <<<608, 64, 0, stream>>>(Am, Ah);
  k_mpk   <<<1600, 256, 0, stream>>>(Ah, Mpk);

  // weight prep
  k_wpack2<<<57, 256, 0, stream>>>(fw2,fw3,fw6,fw7, gw2,gw3,gw6,gw7,
                                   fb2,fb3,fb6,fb7, gb2,gb3,gb6,gb7, wfA, biasPk);
  k_wprepM<<<21, 256, 0, stream>>>(m1w, m2w, m1b, m2b, pkB0, pkB1, biasSum);
  k_wTb   <<<512, 256, 0, stream>>>(skw, wTb);

  // dilated inception -> Xp (7-shift MFMA, channel-minor LDS)
  k_incepM<<<NB*NNODE, 256, 0, stream>>>(x, wfA, biasPk, Xp);

  // transpose Xp -> XpT2 (k-tiled) for hop B staging
  k_xt<<<5120, 256, 0, stream>>>(Xp, XpT2);

  // skip path (MFMA GEMM)
  k_skipM<<<(NB*NNODE)/16, 256, 0, stream>>>(Xp, wTb, skb, xskip, out);

  // pass A: side-A hops, then mix-conv part A written in-place into Xp (bf16 partial)
  k_hop  <<<5120, 256, 0, stream>>>(XpT2, Mpk, H1, H2, 0);
  k_fuse0<<<NB*NNODE, 256, 0, stream>>>(Xp, H1, H2, pkB0, biasSum);

  // pass B: side-B hops, then final accumulate + residual + LN stats (single out write)
  k_hop  <<<5120, 256, 0, stream>>>(XpT2, Mpk, H1, H2, 1);
  k_fuse1<<<NB*NNODE, 256, 0, stream>>>(Xp, H1, H2, out, x, pkB1, part2);

  // layernorm
  k_lnfin<<<1, 32, 0, stream>>>(part2, stats);
  k_lnapply<<<XEL/256, 256, 0, stream>>>(out, stats, lnw, lnb, idxp);
}

// Round 18
// 412.506 us; speedup vs baseline: 1.0207x; 1.0207x over previous
//
#include <hip/hip_runtime.h>
#include <hip/hip_bf16.h>
#include <math.h>

typedef __hip_bfloat16 bf16;
typedef __attribute__((ext_vector_type(8))) short bf16x8;
typedef __attribute__((ext_vector_type(4))) float f32x4;

#define NB 32
#define NC 32
#define NNODE 300
#define NT 64
#define NDIM 40
#define KTOP 20
#define NSKIP 64
#define NTOUT 58
#define SLAB 17400        // NNODE*NTOUT (out layout)
#define BSLAB 556800      // NC*SLAB
#define XEL 17817600      // NB*BSLAB
#define PSLAB 2048        // 64 t x 32 c node slab (channel-minor)
#define BPSLAB 614400     // NNODE*PSLAB
#define XPEL 19660800     // NB*BPSLAB

__device__ __forceinline__ float b2f(bf16 v){ return __bfloat162float(v); }
__device__ __forceinline__ bf16 f2b(float v){ return __float2bfloat16(v); }
__device__ __forceinline__ float fsig(float x){ return 1.0f/(1.0f + __expf(-x)); }
__device__ __forceinline__ float ftanh(float x){ return 2.0f*fsig(2.0f*x) - 1.0f; }

__device__ __forceinline__ unsigned short bbits(float v){
  bf16 h = f2b(v); unsigned short s; __builtin_memcpy(&s, &h, 2); return s;
}

__device__ __forceinline__ uint4 pack8(const float f[8]){
  uint4 d;
  d.x = (unsigned)bbits(f[0]) | ((unsigned)bbits(f[1]) << 16);
  d.y = (unsigned)bbits(f[2]) | ((unsigned)bbits(f[3]) << 16);
  d.z = (unsigned)bbits(f[4]) | ((unsigned)bbits(f[5]) << 16);
  d.w = (unsigned)bbits(f[6]) | ((unsigned)bbits(f[7]) << 16);
  return d;
}

// XCD-aware swizzle for 9600-block kernels
__device__ __forceinline__ void bv_swz(int bid, int& b, int& v){
  int xcd = bid & 7, i = bid >> 3;
  int nb = xcd*1200 + i;
  b = nb / NNODE; v = nb - b*NNODE;
}

// ---------------- graph construction ----------------
__global__ void k_nodes(const float* __restrict__ emb1, const float* __restrict__ emb2,
                        const float* __restrict__ l1w, const float* __restrict__ l1b,
                        const float* __restrict__ l2w, const float* __restrict__ l2b,
                        const int* __restrict__ idxp,
                        float* __restrict__ n1, float* __restrict__ n2){
  int i = blockIdx.x; int d = threadIdx.x;
  if (d >= NDIM) return;
  int r = idxp[i];
  float a1 = l1b[d], a2 = l2b[d];
  for (int k=0;k<NDIM;++k){
    a1 = fmaf(emb1[r*NDIM+k], l1w[d*NDIM+k], a1);
    a2 = fmaf(emb2[r*NDIM+k], l2w[d*NDIM+k], a2);
  }
  n1[i*NDIM+d] = tanhf(3.0f*a1);
  n2[i*NDIM+d] = tanhf(3.0f*a2);
}

__global__ void __launch_bounds__(64) k_adjrow(const float* __restrict__ n1,
                                               const float* __restrict__ n2,
                                               float* __restrict__ Am){
  int i = blockIdx.x; int lane = threadIdx.x;
  __shared__ float rowo[NNODE];
  __shared__ float rowv[NNODE];
  __shared__ int   sel[NNODE];
  for (int j=lane;j<NNODE;j+=64){
    float a = 0.f;
    #pragma unroll
    for (int k=0;k<NDIM;++k){
      float a1 = n1[i*NDIM+k], a2 = n2[i*NDIM+k];
      a = fmaf(a1, n2[j*NDIM+k], a);
      a = fmaf(-a2, n1[j*NDIM+k], a);
    }
    float v = tanhf(3.0f*a);
    v = v > 0.f ? v : 0.f;
    rowo[j]=v; rowv[j]=v; sel[j]=0;
  }
  __syncthreads();
  for (int it=0; it<KTOP; ++it){
    float best = -1.f; int bi = 0x7fffffff;
    for (int j=lane;j<NNODE;j+=64){
      float v = rowv[j];
      if (v > best){ best=v; bi=j; }
    }
    #pragma unroll
    for (int off=32; off; off>>=1){
      float ov = __shfl_xor(best, off);
      int   oi = __shfl_xor(bi, off);
      if (ov > best || (ov == best && oi < bi)){ best=ov; bi=oi; }
    }
    if (lane==0){ sel[bi]=1; rowv[bi]=-2.f; }
    __syncthreads();
  }
  for (int j=lane;j<NNODE;j+=64)
    Am[i*NNODE+j] = sel[j] ? rowo[j] : 0.f;
}

// ---------------- dense normalized adjacency Ah[2][304][304] fp32 (zero-padded) ----------------
__global__ void __launch_bounds__(64) k_norm(const float* __restrict__ Am, float* __restrict__ Ah){
  int r = blockIdx.x;                 // 0..607
  int side = r >= 304; int v = side ? r - 304 : r;
  float* dst = Ah + (size_t)(side ? 304*304 : 0) + v*304;
  int lane = threadIdx.x;
  if (v >= NNODE){
    for (int w=lane; w<304; w+=64) dst[w] = 0.f;
    return;
  }
  float s = 0.f;
  for (int w=lane; w<NNODE; w+=64)
    s += side ? Am[w*NNODE + v] : Am[v*NNODE + w];
  #pragma unroll
  for (int off=32; off; off>>=1) s += __shfl_xor(s, off);
  float inv = 1.0f/(s + 1.0f);        // +1 for the diagonal
  for (int w=lane; w<304; w+=64){
    float a = (w < NNODE) ? (side ? Am[w*NNODE + v] : Am[v*NNODE + w]) : 0.f;
    if (w == v) a += 1.0f;
    dst[w] = a*inv;
  }
}

// ---------------- M matrices -> MFMA A-fragment pack ----------------
// M1 = 0.05I + 0.95*Ah ; M2 = 0.05I + 0.0475*Ah + 0.9025*Ah^2, per side. pm = side*2 + m.
__global__ void k_mpk(const float* __restrict__ Ah, bf16* __restrict__ Mpk){
  int id = blockIdx.x*blockDim.x + threadIdx.x;
  if (id >= 4*320*320) return;
  int pm = id / (320*320);
  int rem = id % (320*320);
  int v = rem / 320, w = rem % 320;
  int s = pm >> 1, m = pm & 1;
  float val = 0.f;
  if (v < 304 && w < 304){
    const float* A = Ah + (size_t)s*304*304;
    float a = A[v*304 + w];
    if (m == 0){
      val = 0.95f*a + (v==w ? 0.05f : 0.f);
    } else {
      float d = 0.f;
      for (int u=0; u<304; ++u) d = fmaf(A[v*304 + u], A[u*304 + w], d);
      val = 0.9025f*d + 0.0475f*a + (v==w ? 0.05f : 0.f);
    }
  }
  int vt16 = v >> 4, lv = v & 15, ks = w >> 5, g = (w >> 3) & 3, j = w & 7;
  int lane = g*16 + lv;
  Mpk[(((size_t)(pm*20 + vt16)*10 + ks)*64 + lane)*8 + j] = f2b(val);
}

// ---------------- inception weights packed per-tap: wfA[((mt*7 + d)*64 + lane)*8 + j] ----------------
__global__ void k_wpack2(const float* __restrict__ fw2,const float* __restrict__ fw3,
                         const float* __restrict__ fw6,const float* __restrict__ fw7,
                         const float* __restrict__ gw2,const float* __restrict__ gw3,
                         const float* __restrict__ gw6,const float* __restrict__ gw7,
                         const float* __restrict__ fb2,const float* __restrict__ fb3,
                         const float* __restrict__ fb6,const float* __restrict__ fb7,
                         const float* __restrict__ gb2,const float* __restrict__ gb3,
                         const float* __restrict__ gb6,const float* __restrict__ gb7,
                         bf16* __restrict__ wfA, float* __restrict__ biasPk){
  int T = blockIdx.x*blockDim.x + threadIdx.x;
  if (T < 14336){
    int j = T & 7;
    int l = (T >> 3) & 63;
    int q = T >> 9;               // 0..27
    int d = q % 7, mt = q / 7;
    int m = mt*16 + (l & 15);
    int ic = (l >> 4)*8 + j;
    int c = m >> 1, path = m & 1;
    int cls = c >> 3, o = c & 7;
    int kk = (cls==0) ? 2 : (cls==1) ? 3 : (cls==2) ? 6 : 7;
    int tp = d - (7 - kk);
    float val = 0.f;
    if (tp >= 0){
      const float* w = (path==0)
        ? (cls==0?fw2:cls==1?fw3:cls==2?fw6:fw7)
        : (cls==0?gw2:cls==1?gw3:cls==2?gw6:gw7);
      val = w[(o*NC + ic)*kk + tp];
    }
    wfA[T] = f2b(val);
  } else if (T < 14336 + 32){
    int c = T - 14336;
    int cls = c >> 3, o = c & 7;
    const float* fb = cls==0?fb2:cls==1?fb3:cls==2?fb6:fb7;
    const float* gb = cls==0?gb2:cls==1?gb3:cls==2?gb6:gb7;
    biasPk[c*2]   = fb[o];
    biasPk[c*2+1] = gb[o];
  }
}

// ---------------- mix conv weights: ONE combined B-fragment buffer, K=160 ----------------
// pkB[((nt*5 + ks)*64 + l)*8 + j]; c = nt*16+(l&15), k = (l>>4)*8+j (0..31)
// ks0: m1w[c,k]+m2w[c,k] (X) | ks1: m1w[c,32+k] (H1a) | ks2: m1w[c,64+k] (H2a)
// ks3: m2w[c,32+k] (H1b)     | ks4: m2w[c,64+k] (H2b)
__global__ void k_wprepM(const float* __restrict__ m1w, const float* __restrict__ m2w,
                         const float* __restrict__ m1b, const float* __restrict__ m2b,
                         bf16* __restrict__ pkB, float* __restrict__ biasSum){
  int id = blockIdx.x*blockDim.x + threadIdx.x;
  if (id < 5120){
    int j = id & 7, l = (id >> 3) & 63, q = id >> 9;   // q = nt*5+ks
    int ks = q % 5, nt = q / 5;
    int k = (l >> 4)*8 + j;
    int c = nt*16 + (l & 15);
    float val;
    if      (ks == 0) val = m1w[c*96 + k] + m2w[c*96 + k];
    else if (ks == 1) val = m1w[c*96 + 32 + k];
    else if (ks == 2) val = m1w[c*96 + 64 + k];
    else if (ks == 3) val = m2w[c*96 + 32 + k];
    else              val = m2w[c*96 + 64 + k];
    pkB[id] = f2b(val);
  } else if (id < 5152){
    int c = id - 5120;
    biasSum[c] = m1b[c] + m2b[c];
  }
}

// ---------------- skip weights packed as MFMA B-fragments ----------------
__global__ void k_wTb(const float* __restrict__ sw, bf16* __restrict__ wTb){
  int id = blockIdx.x*blockDim.x + threadIdx.x;
  if (id >= 131072) return;
  int j = id & 7, l = (id >> 3) & 63, q = id >> 9;  // q = nt*64 + ks
  int ks = q & 63, nt = q >> 6;
  int k = ks*32 + (l >> 4)*8 + j;
  int t = k >> 5, c = k & 31;
  int sc = nt*16 + (l & 15);
  float val = (t < NTOUT) ? sw[sc*1856 + c*NTOUT + t] : 0.f;
  wTb[id] = f2b(val);
}

// ---------------- dilated inception via 7 shifted K=32 MFMAs -> Xp[b][n][t][c] ----------------
__global__ void __launch_bounds__(256) k_incepM(const float* __restrict__ x,
    const bf16* __restrict__ wfA, const float* __restrict__ biasPk,
    bf16* __restrict__ Xp){
  __shared__ unsigned short xcm[72*32];
  int b, n; bv_swz(blockIdx.x, b, n);
  int bn = b*NNODE + n;
  int tid = threadIdx.x;
  {
    int c = tid >> 3, tq = tid & 7, t0 = tq*8;
    const float* src = x + ((size_t)(b*NC + c)*NNODE + n)*NT + t0;
    float4 v0 = *reinterpret_cast<const float4*>(src);
    float4 v1 = *reinterpret_cast<const float4*>(src + 4);
    float f[8] = {v0.x,v0.y,v0.z,v0.w,v1.x,v1.y,v1.z,v1.w};
    int gl = c >> 3, cl = c & 7;
    #pragma unroll
    for (int i=0;i<8;++i){
      int t = t0 + i;
      int pg = gl ^ ((t >> 3) & 3);
      xcm[t*32 + pg*8 + cl] = bbits(f[i]);
    }
    int zt = 64 + (tid >> 5), zic = tid & 31;
    int zpg = (zic >> 3) ^ ((zt >> 3) & 3);
    xcm[zt*32 + zpg*8 + (zic & 7)] = 0;
  }
  __syncthreads();
  int lane = tid & 63;
  int mt = __builtin_amdgcn_readfirstlane(tid >> 6);
  bf16x8 wA[7];
  #pragma unroll
  for (int d=0; d<7; ++d)
    wA[d] = *reinterpret_cast<const bf16x8*>(wfA + (size_t)((mt*7 + d)*64 + lane)*8);
  int g = lane >> 4, col = lane & 15;
  int c0 = mt*8 + 2*g;
  float4 bias2 = *reinterpret_cast<const float4*>(biasPk + c0*2);
  #pragma unroll
  for (int nt=0; nt<4; ++nt){
    int t = col + nt*16;
    f32x4 acc = {0.f, 0.f, 0.f, 0.f};
    #pragma unroll
    for (int d=0; d<7; ++d){
      int tr = t + d;
      int pg = g ^ ((tr >> 3) & 3);
      bf16x8 bfr = *reinterpret_cast<const bf16x8*>(&xcm[tr*32 + pg*8]);
      acc = __builtin_amdgcn_mfma_f32_16x16x32_bf16(wA[d], bfr, acc, 0, 0, 0);
    }
    bool act = t < NTOUT;
    float X0 = act ? (ftanh(acc[0] + bias2.x) * fsig(acc[1] + bias2.y)) : 0.f;
    float X1 = act ? (ftanh(acc[2] + bias2.z) * fsig(acc[3] + bias2.w)) : 0.f;
    unsigned pv = (unsigned)bbits(X0) | ((unsigned)bbits(X1) << 16);
    *reinterpret_cast<unsigned*>(Xp + (size_t)bn*PSLAB + t*32 + c0) = pv;
  }
}

// ---------------- Xp transpose -> XpT2 k-tiled: [b][ctt 16][ks 10][ct_in 128][w_in 32] ----------------
__global__ void __launch_bounds__(256) k_xt(const bf16* __restrict__ Xp, bf16* __restrict__ XpT2){
  __shared__ unsigned short tile[64*66];
  int bid = blockIdx.x;
  int b = bid / 160, r = bid - b*160;
  int wt = r / 32, ctt2 = r - wt*32;
  int w0 = wt*64, ct0 = ctt2*64;
  int tid = threadIdx.x;
  #pragma unroll
  for (int p=0; p<2; ++p){
    int w_in = (tid >> 3) + p*32;
    int ct_in = (tid & 7)*8;
    int w = w0 + w_in;
    uint4 d = (w < NNODE)
      ? *reinterpret_cast<const uint4*>(Xp + (size_t)b*BPSLAB + (size_t)w*PSLAB + ct0 + ct_in)
      : make_uint4(0,0,0,0);
    unsigned short* t = tile + w_in*66 + ct_in;
    *reinterpret_cast<unsigned*>(t)     = d.x;
    *reinterpret_cast<unsigned*>(t + 2) = d.y;
    *reinterpret_cast<unsigned*>(t + 4) = d.z;
    *reinterpret_cast<unsigned*>(t + 6) = d.w;
  }
  __syncthreads();
  #pragma unroll
  for (int p=0; p<2; ++p){
    int ct_in = (tid >> 3) + p*32;
    int wq = tid & 7;
    unsigned short u[8];
    #pragma unroll
    for (int j=0;j<8;++j) u[j] = tile[(wq*8 + j)*66 + ct_in];
    uint4 d;
    d.x = (unsigned)u[0] | ((unsigned)u[1] << 16);
    d.y = (unsigned)u[2] | ((unsigned)u[3] << 16);
    d.z = (unsigned)u[4] | ((unsigned)u[5] << 16);
    d.w = (unsigned)u[6] | ((unsigned)u[7] << 16);
    int ct = ct0 + ct_in;
    int w = w0 + wq*8;
    int ks = w >> 5, w_in32 = w & 31;
    size_t addr = (((size_t)(b*16 + (ct >> 7))*10 + ks) << 12) + ((ct & 127) << 5) + w_in32;
    *reinterpret_cast<uint4*>(XpT2 + addr) = d;
  }
}

// ---------------- skip path via MFMA ----------------
__global__ void __launch_bounds__(256) k_skipM(const bf16* __restrict__ Xp, const bf16* __restrict__ wTb,
      const float* __restrict__ skip_b, const float* __restrict__ x_skip, float* __restrict__ out){
  int bn0 = blockIdx.x * 16;
  int tid = threadIdx.x, lane = tid & 63;
  int nt = __builtin_amdgcn_readfirstlane(tid >> 6);
  int g = lane >> 4, col = lane & 15;
  const bf16* aptr = Xp + (size_t)(bn0 + col)*PSLAB + g*8;
  const bf16* bptr = wTb + ((size_t)nt*64*64 + lane)*8;
  f32x4 acc = {0.f, 0.f, 0.f, 0.f};
  #pragma unroll 4
  for (int ks=0; ks<64; ++ks){
    bf16x8 aF = *reinterpret_cast<const bf16x8*>(aptr + ks*32);
    bf16x8 bF = *reinterpret_cast<const bf16x8*>(bptr + (size_t)ks*512);
    acc = __builtin_amdgcn_mfma_f32_16x16x32_bf16(aF, bF, acc, 0, 0, 0);
  }
  int sc = nt*16 + col;
  float sb = skip_b[sc];
  #pragma unroll
  for (int r=0;r<4;++r){
    int bn = bn0 + g*4 + r;
    int b = bn / NNODE, n = bn - b*NNODE;
    size_t so = (size_t)b*NSKIP*NNODE + (size_t)sc*NNODE + n;
    out[(size_t)XEL + so] = acc[r] + sb + x_skip[so];
  }
}

// ---------------- hop GEMM, BOTH passes in one launch (10240 blocks) ----------------
// H_{m,side}[b] = M_{m,side} x X ; B staged via LDS (pitch 72); passes interleaved per-XCD
__global__ void __launch_bounds__(256) k_hop(const bf16* __restrict__ XpT2,
    const bf16* __restrict__ Mpk,
    bf16* __restrict__ H1a, bf16* __restrict__ H2a,
    bf16* __restrict__ H1b, bf16* __restrict__ H2b){
  __shared__ unsigned short bst[128*72];              // 18 KB, pitch 72 shorts
  __shared__ __align__(16) unsigned short outT[64*136];
  int bid = blockIdx.x;
  int xcd = bid & 7;
  int q = bid >> 3;                 // 0..1279
  int pass = q & 1;
  int i = q >> 1;                   // 0..639
  int nb = xcd*640 + i;
  int b = nb / 160; int r = nb - b*160;
  int m = r / 80; r -= m*80;
  int vt = r >> 4; int ctt = r & 15;
  int ct0 = ctt*128, v0 = vt*64;
  int tid = threadIdx.x, lane = tid & 63;
  int mt = __builtin_amdgcn_readfirstlane(tid >> 6);
  int g = lane >> 4, col = lane & 15;
  const bf16* mbase = Mpk + (((size_t)((pass*2 + m)*20 + vt*4 + mt)*10)*64 + lane)*8;
  bf16x8 aF[10];
  #pragma unroll
  for (int ks=0; ks<10; ++ks)
    aF[ks] = *reinterpret_cast<const bf16x8*>(mbase + (size_t)ks*512);
  const bf16* tb = XpT2 + (((size_t)(b*16 + ctt)*10) << 12);
  int s_ct = tid >> 2, s_w = (tid & 3)*8;
  f32x4 acc[8];
  #pragma unroll
  for (int nt=0; nt<8; ++nt) acc[nt] = (f32x4){0.f,0.f,0.f,0.f};
  for (int ks=0; ks<10; ++ks){
    __syncthreads();
    const bf16* src = tb + ((size_t)ks << 12);
    {
      uint4 d0 = *reinterpret_cast<const uint4*>(src + s_ct*32 + s_w);
      uint4 d1 = *reinterpret_cast<const uint4*>(src + (s_ct+64)*32 + s_w);
      *reinterpret_cast<uint4*>(bst + s_ct*72 + s_w)      = d0;
      *reinterpret_cast<uint4*>(bst + (s_ct+64)*72 + s_w) = d1;
    }
    __syncthreads();
    #pragma unroll
    for (int nt=0; nt<8; ++nt){
      bf16x8 bF = *reinterpret_cast<const bf16x8*>(bst + (nt*16 + col)*72 + g*8);
      acc[nt] = __builtin_amdgcn_mfma_f32_16x16x32_bf16(aF[ks], bF, acc[nt], 0, 0, 0);
    }
  }
  #pragma unroll
  for (int nt=0; nt<8; ++nt){
    #pragma unroll
    for (int r4=0; r4<4; ++r4)
      outT[(mt*16 + g*4 + r4)*136 + nt*16 + col] = bbits(acc[nt][r4]);
  }
  __syncthreads();
  bf16* Hout = pass == 0 ? (m == 0 ? H1a : H2a) : (m == 0 ? H1b : H2b);
  {
    int vl = tid >> 2, e = tid & 3;
    int v = v0 + vl;
    if (v < NNODE){
      bf16* dst = Hout + (size_t)b*BPSLAB + (size_t)v*PSLAB + ct0;
      #pragma unroll
      for (int h=0; h<4; ++h){
        int ctl = e*32 + h*8;
        uint4 d = *reinterpret_cast<const uint4*>(outT + vl*136 + ctl);
        *reinterpret_cast<uint4*>(dst + ctl) = d;
      }
    }
  }
}

// ---------------- merged mix conv (K=160): out = bias + W*[X,H1a,H2a,H1b,H2b] + residual ; LN stats ----------------
__global__ void __launch_bounds__(256) k_fuseM(const bf16* __restrict__ Xp,
    const bf16* __restrict__ H1a, const bf16* __restrict__ H2a,
    const bf16* __restrict__ H1b, const bf16* __restrict__ H2b,
    float* __restrict__ out, const float* __restrict__ x,
    const bf16* __restrict__ pkB, const float* __restrict__ biasSum,
    double* __restrict__ part2){
  __shared__ float redS[4], redS2[4];
  int b, v; bv_swz(blockIdx.x, b, v);
  size_t vbase = (size_t)b*BPSLAB + (size_t)v*PSLAB;
  int tid = threadIdx.x, lane = tid & 63;
  int mt = __builtin_amdgcn_readfirstlane(tid >> 6);
  int g = lane >> 4, col = lane & 15;
  int tRow = mt*16 + col;
  size_t fo = vbase + tRow*32 + g*8;
  bf16x8 aX  = *reinterpret_cast<const bf16x8*>(Xp  + fo);
  bf16x8 a1a = *reinterpret_cast<const bf16x8*>(H1a + fo);
  bf16x8 a2a = *reinterpret_cast<const bf16x8*>(H2a + fo);
  bf16x8 a1b = *reinterpret_cast<const bf16x8*>(H1b + fo);
  bf16x8 a2b = *reinterpret_cast<const bf16x8*>(H2b + fo);
  int t0 = mt*16 + g*4;
  float s = 0.f, s2 = 0.f;
  #pragma unroll
  for (int nt=0; nt<2; ++nt){
    int c_out = nt*16 + col;
    float bv = biasSum[c_out];
    f32x4 acc = {bv, bv, bv, bv};
    bf16x8 w0 = *reinterpret_cast<const bf16x8*>(pkB + (size_t)((nt*5+0)*64 + lane)*8);
    bf16x8 w1 = *reinterpret_cast<const bf16x8*>(pkB + (size_t)((nt*5+1)*64 + lane)*8);
    bf16x8 w2 = *reinterpret_cast<const bf16x8*>(pkB + (size_t)((nt*5+2)*64 + lane)*8);
    bf16x8 w3 = *reinterpret_cast<const bf16x8*>(pkB + (size_t)((nt*5+3)*64 + lane)*8);
    bf16x8 w4 = *reinterpret_cast<const bf16x8*>(pkB + (size_t)((nt*5+4)*64 + lane)*8);
    acc = __builtin_amdgcn_mfma_f32_16x16x32_bf16(aX,  w0, acc, 0, 0, 0);
    acc = __builtin_amdgcn_mfma_f32_16x16x32_bf16(a1a, w1, acc, 0, 0, 0);
    acc = __builtin_amdgcn_mfma_f32_16x16x32_bf16(a2a, w2, acc, 0, 0, 0);
    acc = __builtin_amdgcn_mfma_f32_16x16x32_bf16(a1b, w3, acc, 0, 0, 0);
    acc = __builtin_amdgcn_mfma_f32_16x16x32_bf16(a2b, w4, acc, 0, 0, 0);
    float* po = out + ((size_t)(b*NC + c_out)*NNODE + v)*NTOUT + t0;
    const float* rx = x + ((size_t)(b*NC + c_out)*NNODE + v)*NT + 6 + t0;
    if (t0 <= 54){
      float2 r0 = *reinterpret_cast<const float2*>(rx);
      float2 r1 = *reinterpret_cast<const float2*>(rx + 2);
      float f0 = acc[0] + r0.x, f1 = acc[1] + r0.y;
      float f2v = acc[2] + r1.x, f3 = acc[3] + r1.y;
      *reinterpret_cast<float2*>(po)     = make_float2(f0, f1);
      *reinterpret_cast<float2*>(po + 2) = make_float2(f2v, f3);
      s  += f0 + f1 + f2v + f3;
      s2 += f0*f0 + f1*f1 + f2v*f2v + f3*f3;
    } else if (t0 == 56){
      float2 r0 = *reinterpret_cast<const float2*>(rx);
      float f0 = acc[0] + r0.x, f1 = acc[1] + r0.y;
      *reinterpret_cast<float2*>(po) = make_float2(f0, f1);
      s  += f0 + f1;
      s2 += f0*f0 + f1*f1;
    }
  }
  #pragma unroll
  for (int o=32; o; o>>=1){ s += __shfl_down(s, o); s2 += __shfl_down(s2, o); }
  if (lane == 0){ redS[mt] = s; redS2[mt] = s2; }
  __syncthreads();
  if (tid == 0){
    float as = redS[0]+redS[1]+redS[2]+redS[3];
    float as2 = redS2[0]+redS2[1]+redS2[2]+redS2[3];
    atomicAdd(&part2[b*2],   (double)as);
    atomicAdd(&part2[b*2+1], (double)as2);
  }
}

// ---------------- layernorm ----------------
__global__ void k_lnfin(const double* __restrict__ part2, float* __restrict__ stats){
  int b = threadIdx.x; if (b >= 32) return;
  double s = part2[b*2], s2 = part2[b*2+1];
  double n = (double)BSLAB;
  double mean = s/n;
  double var = s2/n - mean*mean;
  stats[b*2]   = (float)mean;
  stats[b*2+1] = (float)(1.0/sqrt(var + 1e-5));
}

__global__ void __launch_bounds__(256) k_lnapply(float* __restrict__ out, const float* __restrict__ stats,
        const float* __restrict__ lnw, const float* __restrict__ lnb, const int* __restrict__ idxp){
  int o = blockIdx.x*256 + threadIdx.x;
  int t = o % NTOUT; int v = (o / NTOUT) % NNODE; int c = (o / SLAB) % NC; int b = o / BSLAB;
  float mean = stats[b*2], rstd = stats[b*2+1];
  int vn = idxp[v];
  float wv = lnw[((size_t)c*NNODE + vn)*NTOUT + t];
  float bv = lnb[((size_t)c*NNODE + vn)*NTOUT + t];
  float vx = out[o];
  out[o] = (vx - mean)*rstd*wv + bv;
}

extern "C" void kernel_launch(void* const* d_in, const int* in_sizes, int n_in,
                              void* d_out, int out_size, void* d_ws, size_t ws_size,
                              hipStream_t stream) {
  (void)in_sizes; (void)n_in; (void)out_size; (void)ws_size;
  const float* x     = (const float*)d_in[0];
  const float* xskip = (const float*)d_in[1];
  const int*   idxp  = (const int*)d_in[2];
  const float* emb1  = (const float*)d_in[3];
  const float* emb2  = (const float*)d_in[4];
  const float* l1w   = (const float*)d_in[5];
  const float* l1b   = (const float*)d_in[6];
  const float* l2w   = (const float*)d_in[7];
  const float* l2b   = (const float*)d_in[8];
  const float* skw   = (const float*)d_in[9];
  const float* skb   = (const float*)d_in[10];
  const float* m1w   = (const float*)d_in[11];
  const float* m1b   = (const float*)d_in[12];
  const float* m2w   = (const float*)d_in[13];
  const float* m2b   = (const float*)d_in[14];
  const float* lnw   = (const float*)d_in[15];
  const float* lnb   = (const float*)d_in[16];
  const float* fw2=(const float*)d_in[17]; const float* fb2=(const float*)d_in[18];
  const float* gw2=(const float*)d_in[19]; const float* gb2=(const float*)d_in[20];
  const float* fw3=(const float*)d_in[21]; const float* fb3=(const float*)d_in[22];
  const float* gw3=(const float*)d_in[23]; const float* gb3=(const float*)d_in[24];
  const float* fw6=(const float*)d_in[25]; const float* fb6=(const float*)d_in[26];
  const float* gw6=(const float*)d_in[27]; const float* gb6=(const float*)d_in[28];
  const float* fw7=(const float*)d_in[29]; const float* fb7=(const float*)d_in[30];
  const float* gw7=(const float*)d_in[31]; const float* gb7=(const float*)d_in[32];
  float* out = (float*)d_out;

  char* wsbase = (char*)d_ws;
  size_t cur = 0;
  auto alloc = [&](size_t bytes)->char*{
    char* p = wsbase + cur;
    cur = (cur + bytes + 255) & ~(size_t)255;
    return p;
  };
  bf16*  Xp   = (bf16*) alloc((size_t)XPEL*2);
  bf16*  H1a  = (bf16*) alloc((size_t)XPEL*2);
  bf16*  H2a  = (bf16*) alloc((size_t)XPEL*2);
  bf16*  H1b  = (bf16*) alloc((size_t)XPEL*2);
  bf16*  H2b  = (bf16*) alloc((size_t)XPEL*2);
  bf16*  XpT2 = (bf16*) alloc((size_t)NB*16*10*4096*2);
  float* n1   = (float*)alloc(12000*4);
  float* n2   = (float*)alloc(12000*4);
  float* Am   = (float*)alloc(90000*4);
  float* Ah   = (float*)alloc(2*304*304*4);
  bf16*  Mpk  = (bf16*) alloc((size_t)4*20*10*64*8*2);
  bf16*  wTb  = (bf16*) alloc(131072*2);
  bf16*  wfA  = (bf16*) alloc(14336*2);
  float* biasPk = (float*)alloc(64*4);
  bf16*  pkB  = (bf16*) alloc(5120*2);
  float* biasSum = (float*)alloc(32*4);
  double* part2 = (double*)alloc(64*8);
  float* stats = (float*)alloc(64*4);

  hipMemsetAsync(part2, 0, 64*sizeof(double), stream);

  // graph construction
  k_nodes <<<NNODE, 64, 0, stream>>>(emb1, emb2, l1w, l1b, l2w, l2b, idxp, n1, n2);
  k_adjrow<<<NNODE, 64, 0, stream>>>(n1, n2, Am);
  k_norm  <<<608, 64, 0, stream>>>(Am, Ah);
  k_mpk   <<<1600, 256, 0, stream>>>(Ah, Mpk);

  // weight prep
  k_wpack2<<<57, 256, 0, stream>>>(fw2,fw3,fw6,fw7, gw2,gw3,gw6,gw7,
                                   fb2,fb3,fb6,fb7, gb2,gb3,gb6,gb7, wfA, biasPk);
  k_wprepM<<<21, 256, 0, stream>>>(m1w, m2w, m1b, m2b, pkB, biasSum);
  k_wTb   <<<512, 256, 0, stream>>>(skw, wTb);

  // dilated inception -> Xp (7-shift MFMA, channel-minor LDS)
  k_incepM<<<NB*NNODE, 256, 0, stream>>>(x, wfA, biasPk, Xp);

  // transpose Xp -> XpT2 (k-tiled) for hop B staging
  k_xt<<<5120, 256, 0, stream>>>(Xp, XpT2);

  // skip path (MFMA GEMM)
  k_skipM<<<(NB*NNODE)/16, 256, 0, stream>>>(Xp, wTb, skb, xskip, out);

  // all four hops in one launch
  k_hop<<<10240, 256, 0, stream>>>(XpT2, Mpk, H1a, H2a, H1b, H2b);

  // merged mix conv + residual + LN stats, single out write
  k_fuseM<<<NB*NNODE, 256, 0, stream>>>(Xp, H1a, H2a, H1b, H2b, out, x, pkB, biasSum, part2);

  // layernorm
  k_lnfin<<<1, 32, 0, stream>>>(part2, stats);
  k_lnapply<<<XEL/256, 256, 0, stream>>>(out, stats, lnw, lnb, idxp);
}